// Round 1
// baseline (213.960 us; speedup 1.0000x reference)
//
#include <hip/hip_runtime.h>
#include <hip/hip_bf16.h>

typedef float v2f __attribute__((ext_vector_type(2)));

// ---------------- problem constants ----------------
#define B_    4
#define C_    4
#define Q_    8
#define J_    5
#define T_    15
#define NSIG  65536
#define N2SIG 32768
#define NOUT  16384
#define NCH   (B_ * C_)

// ---------------- wavelet filters (constexpr -> inline literals) ----------
constexpr float H0Oc[13] = {
    -0.00455690456024f, -0.00543947593727f,  0.01702522388155f,  0.02382538479492f,
    -0.10671180468666f,  0.01186609203379f,  0.56881042071212f,  0.75614564389252f,
     0.27529538466888f, -0.11720388769911f, -0.03887280126882f,  0.03466034684485f,
    -0.00388321199915f };
constexpr float H1Oc[13] = {
    -0.00388321199915f, -0.03466034684485f, -0.03887280126882f,  0.11720388769911f,
     0.27529538466888f, -0.75614564389252f,  0.56881042071212f, -0.01186609203379f,
    -0.10671180468666f, -0.02382538479492f,  0.01702522388155f,  0.00543947593727f,
    -0.00455690456024f };
constexpr float H0Ac[10] = {
     0.03516384f, 0.0f, -0.08832942f, 0.23389032f, 0.76027237f,
     0.58751830f, 0.0f, -0.11430184f, 0.0f, 0.0f };
constexpr float H0Bc[10] = {
     0.0f, 0.0f, -0.11430184f, 0.0f, 0.58751830f,
     0.76027237f, 0.23389032f, -0.08832942f, 0.0f, 0.03516384f };
constexpr float H1Ac[10] = {
     0.0f, 0.0f, -0.11430184f, 0.0f, 0.58751830f,
    -0.76027237f, 0.23389032f, 0.08832942f, 0.0f, -0.03516384f };
constexpr float H1Bc[10] = {
    -0.03516384f, 0.0f, 0.08832942f, 0.23389032f, -0.76027237f,
     0.58751830f, 0.0f, -0.11430184f, 0.0f, 0.0f };

// fused two-stage lowpass+decimate: out[m] = sum_n g[n] * u[4m + n - 18]
// g[n] = sum_k h[k] * h[n-2k], support 37 taps
struct Gtab { float v[37]; };
constexpr Gtab make_g() {
    Gtab g{};
    for (int n = 0; n < 37; ++n) {
        float s = 0.f;
        for (int k = 0; k < 13; ++k) {
            int l = n - 2 * k;
            if (l >= 0 && l < 13) s += H0Oc[k] * H0Oc[l];
        }
        g.v[n] = s;
    }
    return g;
}
constexpr Gtab cG = make_g();

// ---------------- tiling ----------------
#define M2    256                // final outputs per tile
#define NUcnt 1057               // 4*(M2-1) + 37
#define UPH   266                // phase-plane stride (v2f); 4*UPH = 1064 = old NUP
#define NUP   1064               // U plane stride (v2f elems), = 4*UPH
#define NBcnt 1169               // bp pairs needed
#define NBP   1176
#define S_    1320               // x window (halo 73 left / 74 right)

// LDS carve (floats): [0,1320) X | [1320,2640) L1 | PP0=v2f@0 (1320) |
// PP1=v2f@2640 (1320) | U0=v2f@0 (1064) | U1=v2f@2128 (1064) | sRI=v2f@5280 (1176)
#define SMEM_FLOATS (5280 + 2 * NBP)

__device__ __forceinline__ v2f zmask(v2f a, bool ok) {
    if (!ok) { a.x = 0.f; a.y = 0.f; }
    return a;
}

// phase-split U index: u[i] lives at (i%4)*UPH + i/4.
// write (i = tid + 256k): banks (20*(i&3)+2*(i>>2))%32 -> 4 lanes/bank-pair = b64 minimum (free)
// read (i = 4*tid + n):   per-tap lanes are stride-1 -> free; taps = imm offsets off (up + tid)
__device__ __forceinline__ int uidx(int i) { return (i & 3) * UPH + (i >> 2); }

// ---------------- post stage (u + fused downsample), templated on D ------
template<int D>
__device__ __forceinline__ void post_stage(
        const v2f* __restrict__ sRI, v2f* __restrict__ U0, v2f* __restrict__ U1,
        const float* __restrict__ cw, const float* __restrict__ roots,
        float beta, int j, int b, int c, int m0, int mt, int tid,
        float* __restrict__ out) {
    const float lg_is = -0.5f * (float)j;                // log2(inv_scale)
    const float beta2 = beta * exp2f(0.5f * (float)j);   // beta * scale
    const int   u_lo  = 4 * m0 - 18;

    for (int g2 = 0; g2 < 2; ++g2) {
        // uniform weights / alphas for this group of 4 q's
        float w[4][T_], al[4], cq[4];
        #pragma unroll
        for (int qq = 0; qq < 4; ++qq) {
            const int o = c * Q_ + g2 * 4 + qq;
            #pragma unroll
            for (int t = 0; t < T_; t++) w[qq][t] = cw[(size_t)(j * 32 + o) * T_ + t];
            al[qq] = 1.f / (1.f + __expf(-roots[j * 32 + o]));
            cq[qq] = al[qq] * lg_is;
        }

        // ---- u stage: pk-fma on (R,I) pairs, phase-split writes ----
        for (int i = tid; i < NUcnt; i += 256) {
            const int n = u_lo + i;
            const bool ok = ((unsigned)n < (unsigned)NSIG);
            const v2f* tp = sRI + (i + 56 - 7 * D);
            v2f taps[T_];
            #pragma unroll
            for (int t = 0; t < T_; t++) taps[t] = tp[t * D];
            float uq[4];
            #pragma unroll
            for (int qq = 0; qq < 4; ++qq) {
                v2f ri; ri.x = 0.f; ri.y = 0.f;
                #pragma unroll
                for (int t = 0; t < T_; t++) ri += w[qq][t] * taps[t];
                float z2 = fmaf(ri.x, ri.x, ri.y * ri.y);
                float us = sqrtf(z2);
                float lg = __log2f(us + beta2);
                float u  = exp2f(fmaf(al[qq], lg, cq[qq]));
                uq[qq] = ok ? u : 0.f;
            }
            v2f p0; p0.x = uq[0]; p0.y = uq[1];
            v2f p1; p1.x = uq[2]; p1.y = uq[3];
            const int phi = uidx(i);
            U0[phi] = p0; U1[phi] = p1;
        }
        __syncthreads();

        // ---- fused 37-tap stride-4 downsample, q-pair packed ----
        // phase-split read: tap n of output m=tid lives at up[(n&3)*UPH + (n>>2) + tid]
        // -> per-tap lane-stride-1 (conflict-free), 37 imm offsets off one base
        {
            const int m = m0 + tid;                 // tid < 256 always
            const bool edge = (mt == 0 && tid < 3) || (mt == 63 && tid >= 253);
            #pragma unroll
            for (int qp = 0; qp < 2; ++qp) {
                const v2f* up = qp ? U1 : U0;
                const v2f* ub = up + tid;
                v2f acc; acc.x = 0.f; acc.y = 0.f;
                #pragma unroll
                for (int n = 0; n < 37; ++n)
                    acc += cG.v[n] * ub[(n & 3) * UPH + (n >> 2)];
                if (edge) {
                    // exact two-stage computation honoring v-plane masking
                    v2f a2; a2.x = 0.f; a2.y = 0.f;
                    for (int k = 0; k < 13; ++k) {
                        int p = 2 * m + k - 6;
                        if (p < 0 || p >= N2SIG) continue;
                        v2f v; v.x = 0.f; v.y = 0.f;
                        for (int l = 0; l < 13; ++l)
                            v += H0Oc[l] * up[uidx(4 * tid + 2 * k + l)];
                        a2 += H0Oc[k] * v;
                    }
                    acc = a2;
                }
                const int o = c * Q_ + g2 * 4 + 2 * qp;
                out[((size_t)b * 160 + j * 32 + o)     * NOUT + m] = acc.x;
                out[((size_t)b * 160 + j * 32 + o + 1) * NOUT + m] = acc.y;
            }
        }
        __syncthreads();   // protect U planes before next group's writes
    }
}

// ---------------- fused kernel ----------------
__global__ __launch_bounds__(256, 4) void murenn_all(
        const float* __restrict__ x,
        const float* __restrict__ cw,
        const float* __restrict__ roots,
        const float* __restrict__ beta_p,
        float* __restrict__ out) {
    __shared__ __align__(16) float smem[SMEM_FLOATS];
    float* X   = smem;                       // [0,1320)
    float* L1  = smem + S_;                  // [1320,2640)
    v2f*   PP0 = (v2f*)smem;                 // aliases X/L1 (used after dead)
    v2f*   PP1 = (v2f*)(smem + 2 * S_);      // floats [2640,5280)
    v2f*   U0  = (v2f*)smem;                 // aliases PP region (dead then)
    v2f*   U1  = (v2f*)(smem + 2 * NUP);
    v2f*   sRI = (v2f*)(smem + 4 * S_);      // floats [5280, 5280+2352)

    const int tid = threadIdx.x;
    const int mt  = blockIdx.x;              // 0..63
    const int ch  = blockIdx.y;              // b*C + c
    const int j   = blockIdx.z;              // 0..4
    const int b   = ch >> 2, c = ch & 3;
    const int m0  = mt * M2;
    const int ofs = 4 * m0 - 147;            // window start (bp index 0 at p=73)
    const float beta = beta_p[0];
    const float* xc = x + (size_t)ch * NSIG;

    // ---- load x window ----
    for (int p = tid; p < S_; p += 256) {
        int g = ofs + p;
        X[p] = ((unsigned)g < (unsigned)NSIG) ? xc[g] : 0.f;
    }
    __syncthreads();

    // ---- UDTCWT chain (branches block-uniform in j) ----
    if (j == 0) {
        for (int i = tid; i < NBcnt; i += 256) {
            int p = 73 + i, g = ofs + p;
            float a = 0.f;
            #pragma unroll
            for (int k = 0; k < 13; k++) a += H1Oc[k] * X[p + k - 6];
            if ((unsigned)g >= (unsigned)NSIG) a = 0.f;
            v2f r; r.x = a; r.y = a;
            sRI[i] = r;
        }
    } else {
        // lv0: la1 = conv13(x, H0O) -> L1
        for (int p = 6 + tid; p < 1313; p += 256) {
            int g = ofs + p;
            float a = 0.f;
            #pragma unroll
            for (int k = 0; k < 13; k++) a += H0Oc[k] * X[p + k - 6];
            L1[p] = ((unsigned)g < (unsigned)NSIG) ? a : 0.f;
        }
        __syncthreads();
        if (j == 1) {
            for (int i = tid; i < NBcnt; i += 256) {
                int p = 73 + i, g = ofs + p;
                v2f r; r.x = 0.f; r.y = 0.f;
                #pragma unroll
                for (int k = 0; k < 10; k++) {
                    v2f hk; hk.x = H1Ac[k]; hk.y = H1Bc[k];
                    r += hk * L1[p + k - 4];
                }
                sRI[i] = zmask(r, (unsigned)g < (unsigned)NSIG);
            }
        } else {
            // lv1 (d=1, pad 4): (la2,lb2) -> PP1
            for (int p = 10 + tid; p < 1308; p += 256) {
                int g = ofs + p;
                v2f a; a.x = 0.f; a.y = 0.f;
                #pragma unroll
                for (int k = 0; k < 10; k++) {
                    v2f hk; hk.x = H0Ac[k]; hk.y = H0Bc[k];
                    a += hk * L1[p + k - 4];
                }
                PP1[p] = zmask(a, (unsigned)g < (unsigned)NSIG);
            }
            __syncthreads();
            if (j == 2) {
                for (int i = tid; i < NBcnt; i += 256) {
                    int p = 73 + i, g = ofs + p;
                    v2f r; r.x = 0.f; r.y = 0.f;
                    #pragma unroll
                    for (int k = 0; k < 10; k++) {
                        v2f hk; hk.x = H1Ac[k]; hk.y = H1Bc[k];
                        r += hk * PP1[p + 2 * k - 9];
                    }
                    sRI[i] = zmask(r, (unsigned)g < (unsigned)NSIG);
                }
            } else {
                // lv2 (d=2, pad 9): (la3,lb3) -> PP0  (X/L1 dead)
                for (int p = 19 + tid; p < 1299; p += 256) {
                    int g = ofs + p;
                    v2f a; a.x = 0.f; a.y = 0.f;
                    #pragma unroll
                    for (int k = 0; k < 10; k++) {
                        v2f hk; hk.x = H0Ac[k]; hk.y = H0Bc[k];
                        a += hk * PP1[p + 2 * k - 9];
                    }
                    PP0[p] = zmask(a, (unsigned)g < (unsigned)NSIG);
                }
                __syncthreads();
                if (j == 3) {
                    for (int i = tid; i < NBcnt; i += 256) {
                        int p = 73 + i, g = ofs + p;
                        v2f r; r.x = 0.f; r.y = 0.f;
                        #pragma unroll
                        for (int k = 0; k < 10; k++) {
                            v2f hk; hk.x = H1Ac[k]; hk.y = H1Bc[k];
                            r += hk * PP0[p + 4 * k - 18];
                        }
                        sRI[i] = zmask(r, (unsigned)g < (unsigned)NSIG);
                    }
                } else {
                    // lv3 (d=4, pad 18): (la4,lb4) -> PP1 (old PP1 dead)
                    for (int p = 37 + tid; p < 1281; p += 256) {
                        int g = ofs + p;
                        v2f a; a.x = 0.f; a.y = 0.f;
                        #pragma unroll
                        for (int k = 0; k < 10; k++) {
                            v2f hk; hk.x = H0Ac[k]; hk.y = H0Bc[k];
                            a += hk * PP0[p + 4 * k - 18];
                        }
                        PP1[p] = zmask(a, (unsigned)g < (unsigned)NSIG);
                    }
                    __syncthreads();
                    // j == 4 bandpass (d=8, pad 36)
                    for (int i = tid; i < NBcnt; i += 256) {
                        int p = 73 + i, g = ofs + p;
                        v2f r; r.x = 0.f; r.y = 0.f;
                        #pragma unroll
                        for (int k = 0; k < 10; k++) {
                            v2f hk; hk.x = H1Ac[k]; hk.y = H1Bc[k];
                            r += hk * PP1[p + 8 * k - 36];
                        }
                        sRI[i] = zmask(r, (unsigned)g < (unsigned)NSIG);
                    }
                }
            }
        }
    }
    __syncthreads();
    // PP/X/L1 dead: region becomes U planes.

    if (j == 0)      post_stage<1>(sRI, U0, U1, cw, roots, beta, 0, b, c, m0, mt, tid, out);
    else if (j == 1) post_stage<1>(sRI, U0, U1, cw, roots, beta, 1, b, c, m0, mt, tid, out);
    else if (j == 2) post_stage<2>(sRI, U0, U1, cw, roots, beta, 2, b, c, m0, mt, tid, out);
    else if (j == 3) post_stage<4>(sRI, U0, U1, cw, roots, beta, 3, b, c, m0, mt, tid, out);
    else             post_stage<8>(sRI, U0, U1, cw, roots, beta, 4, b, c, m0, mt, tid, out);
}

// ---------------- launch ----------------
extern "C" void kernel_launch(void* const* d_in, const int* in_sizes, int n_in,
                              void* d_out, int out_size, void* d_ws, size_t ws_size,
                              hipStream_t stream) {
    (void)in_sizes; (void)n_in; (void)out_size; (void)d_ws; (void)ws_size;
    const float* x     = (const float*)d_in[0];
    const float* cw    = (const float*)d_in[1];
    const float* roots = (const float*)d_in[2];
    const float* beta  = (const float*)d_in[3];
    float* out = (float*)d_out;

    dim3 grid(NOUT / M2, NCH, J_);       // (64, 16, 5)
    murenn_all<<<grid, 256, 0, stream>>>(x, cw, roots, beta, out);
}

// Round 2
// 164.091 us; speedup vs baseline: 1.3039x; 1.3039x over previous
//
#include <hip/hip_runtime.h>
#include <hip/hip_bf16.h>

typedef float v2f __attribute__((ext_vector_type(2)));

// ---------------- problem constants ----------------
#define B_    4
#define C_    4
#define Q_    8
#define J_    5
#define T_    15
#define NSIG  65536
#define N2SIG 32768
#define NOUT  16384
#define NCH   (B_ * C_)

// ---------------- wavelet filters (constexpr -> inline literals) ----------
constexpr float H0Oc[13] = {
    -0.00455690456024f, -0.00543947593727f,  0.01702522388155f,  0.02382538479492f,
    -0.10671180468666f,  0.01186609203379f,  0.56881042071212f,  0.75614564389252f,
     0.27529538466888f, -0.11720388769911f, -0.03887280126882f,  0.03466034684485f,
    -0.00388321199915f };
constexpr float H1Oc[13] = {
    -0.00388321199915f, -0.03466034684485f, -0.03887280126882f,  0.11720388769911f,
     0.27529538466888f, -0.75614564389252f,  0.56881042071212f, -0.01186609203379f,
    -0.10671180468666f, -0.02382538479492f,  0.01702522388155f,  0.00543947593727f,
    -0.00455690456024f };
constexpr float H0Ac[10] = {
     0.03516384f, 0.0f, -0.08832942f, 0.23389032f, 0.76027237f,
     0.58751830f, 0.0f, -0.11430184f, 0.0f, 0.0f };
constexpr float H0Bc[10] = {
     0.0f, 0.0f, -0.11430184f, 0.0f, 0.58751830f,
     0.76027237f, 0.23389032f, -0.08832942f, 0.0f, 0.03516384f };
constexpr float H1Ac[10] = {
     0.0f, 0.0f, -0.11430184f, 0.0f, 0.58751830f,
    -0.76027237f, 0.23389032f, 0.08832942f, 0.0f, -0.03516384f };
constexpr float H1Bc[10] = {
    -0.03516384f, 0.0f, 0.08832942f, 0.23389032f, -0.76027237f,
     0.58751830f, 0.0f, -0.11430184f, 0.0f, 0.0f };

// fused two-stage lowpass+decimate: out[m] = sum_n g[n] * u[4m + n - 18]
// g[n] = sum_k h[k] * h[n-2k], support 37 taps
struct Gtab { float v[37]; };
constexpr Gtab make_g() {
    Gtab g{};
    for (int n = 0; n < 37; ++n) {
        float s = 0.f;
        for (int k = 0; k < 13; ++k) {
            int l = n - 2 * k;
            if (l >= 0 && l < 13) s += H0Oc[k] * H0Oc[l];
        }
        g.v[n] = s;
    }
    return g;
}
constexpr Gtab cG = make_g();

// ---------------- tiling ----------------
#define M2    256                // final outputs per tile
#define NUcnt 1057               // 4*(M2-1) + 37
#define NUP   1064               // padded U plane stride (v2f elems)
#define NBcnt 1169               // bp pairs needed
#define NBP   1176
#define S_    1320               // x window (halo 73 left / 74 right)

// LDS carve (floats): [0,1320) X | [1320,2640) L1 | PP0=v2f@0 (1320) |
// PP1=v2f@2640 (1320) | U0=v2f@0 (1064) | U1=v2f@2128 (1064) | sRI=v2f@5280 (1176)
#define SMEM_FLOATS (5280 + 2 * NBP)

__device__ __forceinline__ v2f zmask(v2f a, bool ok) {
    if (!ok) { a.x = 0.f; a.y = 0.f; }
    return a;
}

// ---------------- post stage (u + fused downsample), templated on D ------
// NOTE (round-1 lesson): U-plane layout kept deliberately INTERLEAVED
// (U0[i] linear writes, up[4*tid+n] reads). The 16-way read conflict this
// causes is fully hidden under VALU issue (removing it in r1 cut
// SQ_LDS_BANK_CONFLICT 6.4M->1.35M yet regressed dur 25% by breaking
// per-thread read contiguity / b128 merging). Do not "fix" it again.
template<int D>
__device__ __forceinline__ void post_stage(
        const v2f* __restrict__ sRI, v2f* __restrict__ U0, v2f* __restrict__ U1,
        const float* __restrict__ cw, const float* __restrict__ roots,
        float beta, int j, int b, int c, int m0, int mt, int tid,
        float* __restrict__ out) {
    const float lg_is = -0.5f * (float)j;                // log2(inv_scale)
    const float beta2 = beta * exp2f(0.5f * (float)j);   // beta * scale
    const int   u_lo  = 4 * m0 - 18;

    for (int g2 = 0; g2 < 2; ++g2) {
        // uniform weights / alphas for this group of 4 q's
        float w[4][T_], al[4], cq[4];
        #pragma unroll
        for (int qq = 0; qq < 4; ++qq) {
            const int o = c * Q_ + g2 * 4 + qq;
            #pragma unroll
            for (int t = 0; t < T_; t++) w[qq][t] = cw[(size_t)(j * 32 + o) * T_ + t];
            al[qq] = 1.f / (1.f + __expf(-roots[j * 32 + o]));
            cq[qq] = al[qq] * lg_is;
        }

        // ---- u stage: pk-fma on (R,I) pairs ----
        for (int i = tid; i < NUcnt; i += 256) {
            const int n = u_lo + i;
            const bool ok = ((unsigned)n < (unsigned)NSIG);
            const v2f* tp = sRI + (i + 56 - 7 * D);
            v2f taps[T_];
            #pragma unroll
            for (int t = 0; t < T_; t++) taps[t] = tp[t * D];
            float uq[4];
            #pragma unroll
            for (int qq = 0; qq < 4; ++qq) {
                v2f ri; ri.x = 0.f; ri.y = 0.f;
                #pragma unroll
                for (int t = 0; t < T_; t++) ri += w[qq][t] * taps[t];
                float z2 = fmaf(ri.x, ri.x, ri.y * ri.y);
                // fast single-instruction transcendentals (v_sqrt/v_log/v_exp):
                // default (non-fast-math) sqrtf expands to a ~10-instr IEEE
                // sequence; 1-ulp HW instr is far within absmax tolerance.
                float us = __builtin_amdgcn_sqrtf(z2);
                float lg = __builtin_amdgcn_logf(us + beta2);
                float u  = __builtin_amdgcn_exp2f(fmaf(al[qq], lg, cq[qq]));
                uq[qq] = ok ? u : 0.f;
            }
            v2f p0; p0.x = uq[0]; p0.y = uq[1];
            v2f p1; p1.x = uq[2]; p1.y = uq[3];
            U0[i] = p0; U1[i] = p1;
        }
        __syncthreads();

        // ---- fused 37-tap stride-4 downsample, q-pair packed ----
        {
            const int m = m0 + tid;                 // tid < 256 always
            const bool edge = (mt == 0 && tid < 3) || (mt == 63 && tid >= 253);
            #pragma unroll
            for (int qp = 0; qp < 2; ++qp) {
                const v2f* up = qp ? U1 : U0;
                v2f acc; acc.x = 0.f; acc.y = 0.f;
                #pragma unroll
                for (int n = 0; n < 37; ++n) acc += cG.v[n] * up[4 * tid + n];
                if (edge) {
                    // exact two-stage computation honoring v-plane masking
                    v2f a2; a2.x = 0.f; a2.y = 0.f;
                    for (int k = 0; k < 13; ++k) {
                        int p = 2 * m + k - 6;
                        if (p < 0 || p >= N2SIG) continue;
                        v2f v; v.x = 0.f; v.y = 0.f;
                        for (int l = 0; l < 13; ++l)
                            v += H0Oc[l] * up[4 * tid + 2 * k + l];
                        a2 += H0Oc[k] * v;
                    }
                    acc = a2;
                }
                const int o = c * Q_ + g2 * 4 + 2 * qp;
                out[((size_t)b * 160 + j * 32 + o)     * NOUT + m] = acc.x;
                out[((size_t)b * 160 + j * 32 + o + 1) * NOUT + m] = acc.y;
            }
        }
        __syncthreads();   // protect U planes before next group's writes
    }
}

// ---------------- fused kernel ----------------
// launch_bounds min-waves/EU = 5: LDS 30720B x 5 = 150KB <= 160KB, so a 5th
// block/CU is LDS-feasible; measured occupancy averaged only ~3.5 blocks.
__global__ __launch_bounds__(256, 5) void murenn_all(
        const float* __restrict__ x,
        const float* __restrict__ cw,
        const float* __restrict__ roots,
        const float* __restrict__ beta_p,
        float* __restrict__ out) {
    __shared__ __align__(16) float smem[SMEM_FLOATS];
    float* X   = smem;                       // [0,1320)
    float* L1  = smem + S_;                  // [1320,2640)
    v2f*   PP0 = (v2f*)smem;                 // aliases X/L1 (used after dead)
    v2f*   PP1 = (v2f*)(smem + 2 * S_);      // floats [2640,5280)
    v2f*   U0  = (v2f*)smem;                 // aliases PP region (dead then)
    v2f*   U1  = (v2f*)(smem + 2 * NUP);
    v2f*   sRI = (v2f*)(smem + 4 * S_);      // floats [5280, 5280+2352)

    const int tid = threadIdx.x;
    // j varies FASTEST in dispatch order: mixes the 5x work-imbalanced j
    // cohorts across CUs (kills the long-j tail) and makes the 5 blocks
    // sharing one x-window dispatch-adjacent (L2 locality).
    const int j   = blockIdx.x;              // 0..4
    const int mt  = blockIdx.y;              // 0..63
    const int ch  = blockIdx.z;              // b*C + c
    const int b   = ch >> 2, c = ch & 3;
    const int m0  = mt * M2;
    const int ofs = 4 * m0 - 147;            // window start (bp index 0 at p=73)
    const float beta = beta_p[0];
    const float* xc = x + (size_t)ch * NSIG;

    // ---- load x window ----
    for (int p = tid; p < S_; p += 256) {
        int g = ofs + p;
        X[p] = ((unsigned)g < (unsigned)NSIG) ? xc[g] : 0.f;
    }
    __syncthreads();

    // ---- UDTCWT chain (branches block-uniform in j) ----
    if (j == 0) {
        for (int i = tid; i < NBcnt; i += 256) {
            int p = 73 + i, g = ofs + p;
            float a = 0.f;
            #pragma unroll
            for (int k = 0; k < 13; k++) a += H1Oc[k] * X[p + k - 6];
            if ((unsigned)g >= (unsigned)NSIG) a = 0.f;
            v2f r; r.x = a; r.y = a;
            sRI[i] = r;
        }
    } else {
        // lv0: la1 = conv13(x, H0O) -> L1
        for (int p = 6 + tid; p < 1313; p += 256) {
            int g = ofs + p;
            float a = 0.f;
            #pragma unroll
            for (int k = 0; k < 13; k++) a += H0Oc[k] * X[p + k - 6];
            L1[p] = ((unsigned)g < (unsigned)NSIG) ? a : 0.f;
        }
        __syncthreads();
        if (j == 1) {
            for (int i = tid; i < NBcnt; i += 256) {
                int p = 73 + i, g = ofs + p;
                v2f r; r.x = 0.f; r.y = 0.f;
                #pragma unroll
                for (int k = 0; k < 10; k++) {
                    v2f hk; hk.x = H1Ac[k]; hk.y = H1Bc[k];
                    r += hk * L1[p + k - 4];
                }
                sRI[i] = zmask(r, (unsigned)g < (unsigned)NSIG);
            }
        } else {
            // lv1 (d=1, pad 4): (la2,lb2) -> PP1
            for (int p = 10 + tid; p < 1308; p += 256) {
                int g = ofs + p;
                v2f a; a.x = 0.f; a.y = 0.f;
                #pragma unroll
                for (int k = 0; k < 10; k++) {
                    v2f hk; hk.x = H0Ac[k]; hk.y = H0Bc[k];
                    a += hk * L1[p + k - 4];
                }
                PP1[p] = zmask(a, (unsigned)g < (unsigned)NSIG);
            }
            __syncthreads();
            if (j == 2) {
                for (int i = tid; i < NBcnt; i += 256) {
                    int p = 73 + i, g = ofs + p;
                    v2f r; r.x = 0.f; r.y = 0.f;
                    #pragma unroll
                    for (int k = 0; k < 10; k++) {
                        v2f hk; hk.x = H1Ac[k]; hk.y = H1Bc[k];
                        r += hk * PP1[p + 2 * k - 9];
                    }
                    sRI[i] = zmask(r, (unsigned)g < (unsigned)NSIG);
                }
            } else {
                // lv2 (d=2, pad 9): (la3,lb3) -> PP0  (X/L1 dead)
                for (int p = 19 + tid; p < 1299; p += 256) {
                    int g = ofs + p;
                    v2f a; a.x = 0.f; a.y = 0.f;
                    #pragma unroll
                    for (int k = 0; k < 10; k++) {
                        v2f hk; hk.x = H0Ac[k]; hk.y = H0Bc[k];
                        a += hk * PP1[p + 2 * k - 9];
                    }
                    PP0[p] = zmask(a, (unsigned)g < (unsigned)NSIG);
                }
                __syncthreads();
                if (j == 3) {
                    for (int i = tid; i < NBcnt; i += 256) {
                        int p = 73 + i, g = ofs + p;
                        v2f r; r.x = 0.f; r.y = 0.f;
                        #pragma unroll
                        for (int k = 0; k < 10; k++) {
                            v2f hk; hk.x = H1Ac[k]; hk.y = H1Bc[k];
                            r += hk * PP0[p + 4 * k - 18];
                        }
                        sRI[i] = zmask(r, (unsigned)g < (unsigned)NSIG);
                    }
                } else {
                    // lv3 (d=4, pad 18): (la4,lb4) -> PP1 (old PP1 dead)
                    for (int p = 37 + tid; p < 1281; p += 256) {
                        int g = ofs + p;
                        v2f a; a.x = 0.f; a.y = 0.f;
                        #pragma unroll
                        for (int k = 0; k < 10; k++) {
                            v2f hk; hk.x = H0Ac[k]; hk.y = H0Bc[k];
                            a += hk * PP0[p + 4 * k - 18];
                        }
                        PP1[p] = zmask(a, (unsigned)g < (unsigned)NSIG);
                    }
                    __syncthreads();
                    // j == 4 bandpass (d=8, pad 36)
                    for (int i = tid; i < NBcnt; i += 256) {
                        int p = 73 + i, g = ofs + p;
                        v2f r; r.x = 0.f; r.y = 0.f;
                        #pragma unroll
                        for (int k = 0; k < 10; k++) {
                            v2f hk; hk.x = H1Ac[k]; hk.y = H1Bc[k];
                            r += hk * PP1[p + 8 * k - 36];
                        }
                        sRI[i] = zmask(r, (unsigned)g < (unsigned)NSIG);
                    }
                }
            }
        }
    }
    __syncthreads();
    // PP/X/L1 dead: region becomes U planes.

    if (j == 0)      post_stage<1>(sRI, U0, U1, cw, roots, beta, 0, b, c, m0, mt, tid, out);
    else if (j == 1) post_stage<1>(sRI, U0, U1, cw, roots, beta, 1, b, c, m0, mt, tid, out);
    else if (j == 2) post_stage<2>(sRI, U0, U1, cw, roots, beta, 2, b, c, m0, mt, tid, out);
    else if (j == 3) post_stage<4>(sRI, U0, U1, cw, roots, beta, 3, b, c, m0, mt, tid, out);
    else             post_stage<8>(sRI, U0, U1, cw, roots, beta, 4, b, c, m0, mt, tid, out);
}

// ---------------- launch ----------------
extern "C" void kernel_launch(void* const* d_in, const int* in_sizes, int n_in,
                              void* d_out, int out_size, void* d_ws, size_t ws_size,
                              hipStream_t stream) {
    (void)in_sizes; (void)n_in; (void)out_size; (void)d_ws; (void)ws_size;
    const float* x     = (const float*)d_in[0];
    const float* cw    = (const float*)d_in[1];
    const float* roots = (const float*)d_in[2];
    const float* beta  = (const float*)d_in[3];
    float* out = (float*)d_out;

    dim3 grid(J_, NOUT / M2, NCH);       // (5, 64, 16), j fastest
    murenn_all<<<grid, 256, 0, stream>>>(x, cw, roots, beta, out);
}